// Round 2
// baseline (1265.426 us; speedup 1.0000x reference)
//
#include <hip/hip_runtime.h>

typedef unsigned short u16;
typedef __bf16 bf16x8 __attribute__((ext_vector_type(8)));
typedef float f32x4 __attribute__((ext_vector_type(4)));

__device__ __forceinline__ float b2f(u16 u) { return __builtin_bit_cast(float, (unsigned)u << 16); }
__device__ __forceinline__ u16 f2b(float f) {
  unsigned x = __builtin_bit_cast(unsigned, f);
  x += 0x7fffu + ((x >> 16) & 1u);
  return (u16)(x >> 16);
}

__device__ __forceinline__ void gload16(const u16* g, u16* l) {
  auto gp = (__attribute__((address_space(1))) void*)(void*)const_cast<u16*>(g);
  auto lp = (__attribute__((address_space(3))) void*)(void*)l;
  __builtin_amdgcn_global_load_lds(gp, lp, 16, 0, 0);
}

__device__ __forceinline__ f32x4 mfma16(bf16x8 a, bf16x8 b, f32x4 c) {
  return __builtin_amdgcn_mfma_f32_16x16x32_bf16(a, b, c, 0, 0, 0);
}

// ---------------- weight transpose (R x C) f32 -> (C x R) bf16 ----------------
__global__ __launch_bounds__(256) void transpose_k(const float* __restrict__ in, u16* __restrict__ out,
                                                   int R, int C) {
  __shared__ float tile[32][33];
  const int bx = blockIdx.x * 32, by = blockIdx.y * 32;
  const int x = threadIdx.x;
  for (int yy = threadIdx.y; yy < 32; yy += 8) tile[yy][x] = in[(size_t)(by + yy) * C + bx + x];
  __syncthreads();
  for (int yy = threadIdx.y; yy < 32; yy += 8) out[(size_t)(bx + yy) * R + by + x] = f2b(tile[x][yy]);
}

// ---------------- BN on row 0 of each batch (f32 -> f32) ----------------
__global__ __launch_bounds__(256) void bn_kernel(const float* __restrict__ feats, int Lrow,
                                                 const float* g, const float* b, const float* m, const float* v,
                                                 float* __restrict__ out) {
  const int bb = blockIdx.x;
  const float* row = feats + (size_t)bb * Lrow * 768;
  for (int d = threadIdx.x; d < 768; d += 256) {
    float x = row[d];
    out[bb * 768 + d] = (x - m[d]) * (1.0f / sqrtf(v[d] + 1e-5f)) * g[d] + b[d];
  }
}

// ---------------- stable top-k selection (rank-based) ----------------
__global__ __launch_bounds__(256) void topk_sel(const float* __restrict__ score, int L, int Ksel,
                                                int* __restrict__ sel1, int* __restrict__ sel2, int Lq) {
  __shared__ float s[256];
  const int b = blockIdx.x;
  for (int i = threadIdx.x; i < L; i += 256) {
    float v = score[b * L + i];
    s[i] = (i == 0) ? 0.0f : v;
  }
  __syncthreads();
  for (int i = threadIdx.x; i < L; i += 256) {
    float si = s[i];
    int rank = 0;
    for (int j = 0; j < L; ++j) {
      float sj = s[j];
      rank += (sj > si) || (sj == si && j < i);
    }
    if (rank < Ksel) sel1[b * Lq + rank + 1] = i;
    else if (rank < 2 * Ksel) sel2[b * Lq + (rank - Ksel) + 1] = i;
  }
  if (threadIdx.x == 0) { sel1[b * Lq] = 0; sel2[b * Lq] = 0; }
}

// ---------------- LayerNorm (f32 in -> bf16 out), one wave per 768-row ----------------
__global__ __launch_bounds__(256) void ln_rows(const float* __restrict__ x, const float* g, const float* b,
                                               u16* __restrict__ out) {
  const int row = blockIdx.x * 4 + (threadIdx.x >> 6);
  const int l = threadIdx.x & 63;
  const float* xr = x + (size_t)row * 768;
  float v[12]; float s = 0.f;
#pragma unroll
  for (int i = 0; i < 12; ++i) { v[i] = xr[l + i * 64]; s += v[i]; }
  for (int d = 1; d < 64; d <<= 1) s += __shfl_xor(s, d);
  const float mu = s * (1.0f / 768.0f);
  float q = 0.f;
#pragma unroll
  for (int i = 0; i < 12; ++i) { float t = v[i] - mu; q += t * t; }
  for (int d = 1; d < 64; d <<= 1) q += __shfl_xor(q, d);
  const float rs = 1.0f / sqrtf(q * (1.0f / 768.0f) + 1e-5f);
#pragma unroll
  for (int i = 0; i < 12; ++i) {
    int c = l + i * 64;
    out[(size_t)row * 768 + c] = f2b((v[i] - mu) * rs * g[c] + b[c]);
  }
}

// ---------------- gather selected rows (qn bf16 from kn, xs f32 from feats) ----------------
__global__ __launch_bounds__(128) void gather_kernel(const int* __restrict__ sel, const u16* __restrict__ kn,
                                                     const float* __restrict__ feats, u16* __restrict__ qn,
                                                     float* __restrict__ xs, int Lq, int Lsrc) {
  const int p = blockIdx.x, b = blockIdx.y;
  const int src = sel[b * Lq + p];
  const uint4* sq = (const uint4*)(kn + ((size_t)b * Lsrc + src) * 768);
  uint4* dq = (uint4*)(qn + ((size_t)b * Lq + p) * 768);
  for (int c = threadIdx.x; c < 96; c += 128) dq[c] = sq[c];
  const float4* sx = (const float4*)(feats + ((size_t)b * Lsrc + src) * 768);
  float4* dx = (float4*)(xs + ((size_t)b * Lq + p) * 768);
  for (int c = threadIdx.x; c < 192; c += 128) dx[c] = sx[c];
}

// ---------------- GEMM: C = A(MxK) * Bt(NxK)^T, fused epilogues ----------------
// EPI_PLAIN:  out bf16 = acc + bias
// EPI_QSCALE: out bf16 = (acc + bias) * 0.125
// EPI_GELU:   out bf16 = gelu(acc + bias)
// EPI_RES_FADD: out f32 = acc + bias + res_f32      (x + att)
// EPI_RES_OUT:  out f32 = acc + bias + res_f32      (final output)
enum { EPI_PLAIN = 0, EPI_QSCALE = 1, EPI_GELU = 2, EPI_RES_FADD = 3, EPI_RES_OUT = 4 };

template <int EPI>
__global__ __launch_bounds__(256) void gemm_bt(const u16* __restrict__ A, const u16* __restrict__ Bt,
                                               const float* __restrict__ bias, const float* __restrict__ res,
                                               void* __restrict__ outp, int M, int N, int K) {
  __shared__ alignas(16) u16 As[128 * 32];
  __shared__ alignas(16) u16 Bs[128 * 32];
  const int tid = threadIdx.x, l = tid & 63, w = tid >> 6;
  const int m0 = blockIdx.y * 128, n0 = blockIdx.x * 128;
  const int wm = (w & 1) * 64, wn = (w >> 1) * 64;
  f32x4 acc[4][4] = {};
  const int sm = tid >> 2, sk = (tid & 3) * 8;
  const u16* aG = A + (size_t)(m0 + sm) * K + sk;
  const u16* bG = Bt + (size_t)(n0 + sm) * K + sk;
  const size_t rowK64 = (size_t)64 * K;
  for (int k0 = 0; k0 < K; k0 += 32) {
    gload16(aG + k0, &As[tid * 8]);
    gload16(aG + k0 + rowK64, &As[tid * 8 + 2048]);
    gload16(bG + k0, &Bs[tid * 8]);
    gload16(bG + k0 + rowK64, &Bs[tid * 8 + 2048]);
    __syncthreads();
    bf16x8 af[4], bfr[4];
#pragma unroll
    for (int i = 0; i < 4; ++i) af[i] = *(const bf16x8*)&As[(wm + i * 16 + (l & 15)) * 32 + (l >> 4) * 8];
#pragma unroll
    for (int i = 0; i < 4; ++i) bfr[i] = *(const bf16x8*)&Bs[(wn + i * 16 + (l & 15)) * 32 + (l >> 4) * 8];
#pragma unroll
    for (int mi = 0; mi < 4; ++mi)
#pragma unroll
      for (int ni = 0; ni < 4; ++ni) acc[mi][ni] = mfma16(af[mi], bfr[ni], acc[mi][ni]);
    __syncthreads();
  }
  const int r4 = (l >> 4) * 4, c16 = l & 15;
#pragma unroll
  for (int mi = 0; mi < 4; ++mi) {
#pragma unroll
    for (int ni = 0; ni < 4; ++ni) {
      const int gn = n0 + wn + ni * 16 + c16;
      const float bia = bias[gn];
#pragma unroll
      for (int j = 0; j < 4; ++j) {
        const int gm = m0 + wm + mi * 16 + r4 + j;
        const size_t off = (size_t)gm * N + gn;
        float v = acc[mi][ni][j] + bia;
        if constexpr (EPI == EPI_QSCALE) {
          ((u16*)outp)[off] = f2b(v * 0.125f);
        } else if constexpr (EPI == EPI_GELU) {
          ((u16*)outp)[off] = f2b(0.5f * v * (1.0f + erff(v * 0.70710678118654752f)));
        } else if constexpr (EPI == EPI_RES_FADD || EPI == EPI_RES_OUT) {
          ((float*)outp)[off] = v + res[off];
        } else {
          ((u16*)outp)[off] = f2b(v);
        }
      }
    }
  }
}

// ---------------- attention: one WG per (b, h); bf16 in (Q,K,V), bf16 out ----------------
template <int LQP, int LKP, int LQ, int LK, bool MASK>
__global__ __launch_bounds__(256) void attn_kernel(const u16* __restrict__ Q, const u16* __restrict__ Kb,
                                                   const u16* __restrict__ Vb, const int* __restrict__ tokens,
                                                   u16* __restrict__ O) {
  const int b = blockIdx.y, h = blockIdx.x;
  const int tid = threadIdx.x, l = tid & 63, w = tid >> 6;
  __shared__ alignas(16) u16 Qs[LQP][64];
  __shared__ alignas(16) u16 Ks[LKP][64];
  __shared__ alignas(16) u16 VTs[64][LKP];
  __shared__ float Ss[LQP][LKP];
  __shared__ alignas(16) u16 Ps[LQP][LKP];
  __shared__ int tokLds[MASK ? LKP : 1];

  for (int c = tid; c < LQP * 8; c += 256) {
    int q = c >> 3, d8 = c & 7;
    uint4 val = {0, 0, 0, 0};
    if (q < LQ) val = *(const uint4*)(Q + ((size_t)(b * LQ + q)) * 768 + h * 64 + d8 * 8);
    *(uint4*)&Qs[q][d8 * 8] = val;
  }
  for (int c = tid; c < LKP * 8; c += 256) {
    int k = c >> 3, d8 = c & 7;
    uint4 val = {0, 0, 0, 0};
    if (k < LK) val = *(const uint4*)(Kb + ((size_t)(b * LK + k)) * 768 + h * 64 + d8 * 8);
    *(uint4*)&Ks[k][d8 * 8] = val;
  }
  for (int c = tid; c < LKP * 8; c += 256) {
    int k = c >> 3, d8 = c & 7;
    alignas(16) u16 tmp[8] = {0, 0, 0, 0, 0, 0, 0, 0};
    if (k < LK) *(uint4*)tmp = *(const uint4*)(Vb + ((size_t)(b * LK + k)) * 768 + h * 64 + d8 * 8);
#pragma unroll
    for (int j = 0; j < 8; ++j) VTs[d8 * 8 + j][k] = tmp[j];
  }
  if (MASK)
    for (int c = tid; c < LKP; c += 256) tokLds[c] = (c < LK) ? tokens[b * LK + c] : 1;
  __syncthreads();

  // QK^T
  for (int nt = w; nt < LKP / 16; nt += 4) {
#pragma unroll
    for (int mt = 0; mt < LQP / 16; ++mt) {
      f32x4 a_ = {0.f, 0.f, 0.f, 0.f};
#pragma unroll
      for (int kk = 0; kk < 64; kk += 32) {
        bf16x8 av = *(const bf16x8*)&Qs[mt * 16 + (l & 15)][kk + (l >> 4) * 8];
        bf16x8 bv = *(const bf16x8*)&Ks[nt * 16 + (l & 15)][kk + (l >> 4) * 8];
        a_ = mfma16(av, bv, a_);
      }
#pragma unroll
      for (int j = 0; j < 4; ++j) Ss[mt * 16 + (l >> 4) * 4 + j][nt * 16 + (l & 15)] = a_[j];
    }
  }
  __syncthreads();

  // softmax per row
  constexpr int NCH = (LKP + 63) / 64;
  for (int r = w; r < LQP; r += 4) {
    if (r >= LQ) {
#pragma unroll
      for (int i = 0; i < NCH; ++i) {
        int c = l + (i << 6);
        if (c < LKP) Ps[r][c] = 0;
      }
      continue;
    }
    float sv[NCH];
    float mx = -INFINITY;
#pragma unroll
    for (int i = 0; i < NCH; ++i) {
      int c = l + (i << 6);
      float s = -INFINITY;
      if (c < LKP && c < LK) {
        s = Ss[r][c];
        if (MASK && tokLds[c] == 0) s = -1e9f;
      }
      sv[i] = s;
      mx = fmaxf(mx, s);
    }
    for (int d = 1; d < 64; d <<= 1) mx = fmaxf(mx, __shfl_xor(mx, d));
    float sum = 0.f;
#pragma unroll
    for (int i = 0; i < NCH; ++i) { float e = __expf(sv[i] - mx); sv[i] = e; sum += e; }
    for (int d = 1; d < 64; d <<= 1) sum += __shfl_xor(sum, d);
    const float inv = 1.0f / sum;
#pragma unroll
    for (int i = 0; i < NCH; ++i) {
      int c = l + (i << 6);
      if (c < LKP) Ps[r][c] = f2b(sv[i] * inv);
    }
  }
  __syncthreads();

  // P*V
  for (int mt = w; mt < LQP / 16; mt += 4) {
#pragma unroll
    for (int nt = 0; nt < 4; ++nt) {
      f32x4 a_ = {0.f, 0.f, 0.f, 0.f};
#pragma unroll
      for (int kk = 0; kk < LKP; kk += 32) {
        bf16x8 av = *(const bf16x8*)&Ps[mt * 16 + (l & 15)][kk + (l >> 4) * 8];
        bf16x8 bv = *(const bf16x8*)&VTs[nt * 16 + (l & 15)][kk + (l >> 4) * 8];
        a_ = mfma16(av, bv, a_);
      }
#pragma unroll
      for (int j = 0; j < 4; ++j) {
        int r = mt * 16 + (l >> 4) * 4 + j;
        if (r < LQ) O[((size_t)(b * LQ + r)) * 768 + h * 64 + nt * 16 + (l & 15)] = f2b(a_[j]);
      }
    }
  }
}

// ---------------------------------------------------------------
extern "C" void kernel_launch(void* const* d_in, const int* in_sizes, int n_in,
                              void* d_out, int out_size, void* d_ws, size_t ws_size,
                              hipStream_t stream) {
  (void)in_sizes; (void)n_in; (void)out_size; (void)ws_size;
  const float* image_feats = (const float*)d_in[0];
  const float* image_att = (const float*)d_in[1];
  const float* text_feats = (const float*)d_in[2];
  const float* text_att = (const float*)d_in[3];
  const int* tokens = (const int*)d_in[4];
  const float* bn_img_g = (const float*)d_in[5];
  const float* bn_img_b = (const float*)d_in[6];
  const float* bn_img_m = (const float*)d_in[7];
  const float* bn_img_v = (const float*)d_in[8];
  const float* bn_txt_g = (const float*)d_in[9];
  const float* bn_txt_b = (const float*)d_in[10];
  const float* bn_txt_m = (const float*)d_in[11];
  const float* bn_txt_v = (const float*)d_in[12];
  const float* ln1_g = (const float*)d_in[13];
  const float* ln1_b = (const float*)d_in[14];
  const float* ln2_g = (const float*)d_in[15];
  const float* ln2_b = (const float*)d_in[16];
  const float* Wq = (const float*)d_in[17];
  const float* Wk = (const float*)d_in[18];
  const float* Wv = (const float*)d_in[19];
  const float* Wo = (const float*)d_in[20];
  const float* bq = (const float*)d_in[21];
  const float* bk = (const float*)d_in[22];
  const float* bv = (const float*)d_in[23];
  const float* bo = (const float*)d_in[24];
  const float* W1 = (const float*)d_in[25];
  const float* b1 = (const float*)d_in[26];
  const float* W2 = (const float*)d_in[27];
  const float* b2 = (const float*)d_in[28];

  float* out = (float*)d_out;
  char* wsp = (char*)d_ws;
  size_t off = 0;
  auto alloc = [&](size_t bytes) -> void* {
    void* p = wsp + off;
    off += (bytes + 255) & ~(size_t)255;
    return p;
  };
  u16* WqT = (u16*)alloc(768 * 768 * 2);
  u16* WkT = (u16*)alloc(768 * 768 * 2);
  u16* WvT = (u16*)alloc(768 * 768 * 2);
  u16* WoT = (u16*)alloc(768 * 768 * 2);
  u16* W1T = (u16*)alloc((size_t)768 * 3072 * 2);
  u16* W2T = (u16*)alloc((size_t)768 * 3072 * 2);
  u16* kn = (u16*)alloc((size_t)25216 * 768 * 2);
  u16* Kb = (u16*)alloc((size_t)25216 * 768 * 2);
  u16* Vb = (u16*)alloc((size_t)25216 * 768 * 2);
  int* sel_i1 = (int*)alloc(128 * 60 * 4);
  int* sel_i2 = (int*)alloc(128 * 60 * 4);
  int* sel_t1 = (int*)alloc(128 * 20 * 4);
  int* sel_t2 = (int*)alloc(128 * 20 * 4);
  u16* qn = (u16*)alloc((size_t)7680 * 768 * 2);  // LN'd Q rows; later reused as att-out
  float* xs = (float*)alloc((size_t)7680 * 768 * 4);  // gathered residual (exact f32)
  u16* Qb = (u16*)alloc((size_t)7680 * 768 * 2);      // Q proj; later reused as h (LN2 out)
  float* x1 = (float*)alloc((size_t)7680 * 768 * 4);  // x + att (f32)
  u16* gb = (u16*)alloc((size_t)7680 * 3072 * 2);     // gelu(h@W1+b1)

  const dim3 tb(32, 8);
  transpose_k<<<dim3(24, 24), tb, 0, stream>>>(Wq, WqT, 768, 768);
  transpose_k<<<dim3(24, 24), tb, 0, stream>>>(Wk, WkT, 768, 768);
  transpose_k<<<dim3(24, 24), tb, 0, stream>>>(Wv, WvT, 768, 768);
  transpose_k<<<dim3(24, 24), tb, 0, stream>>>(Wo, WoT, 768, 768);
  transpose_k<<<dim3(96, 24), tb, 0, stream>>>(W1, W1T, 768, 3072);
  transpose_k<<<dim3(24, 96), tb, 0, stream>>>(W2, W2T, 3072, 768);

  bn_kernel<<<128, 256, 0, stream>>>(image_feats, 197, bn_img_g, bn_img_b, bn_img_m, bn_img_v, out);
  bn_kernel<<<128, 256, 0, stream>>>(text_feats, 64, bn_txt_g, bn_txt_b, bn_txt_m, bn_txt_v, out + 98304);

  topk_sel<<<128, 256, 0, stream>>>(image_att, 197, 59, sel_i1, sel_i2, 60);
  topk_sel<<<128, 256, 0, stream>>>(text_att, 64, 19, sel_t1, sel_t2, 20);

  // ---- image modality ----
  ln_rows<<<25216 / 4, 256, 0, stream>>>(image_feats, ln1_g, ln1_b, kn);
  gemm_bt<EPI_PLAIN><<<dim3(6, 197), 256, 0, stream>>>(kn, WkT, bk, nullptr, Kb, 25216, 768, 768);
  gemm_bt<EPI_PLAIN><<<dim3(6, 197), 256, 0, stream>>>(kn, WvT, bv, nullptr, Vb, 25216, 768, 768);
  for (int p = 0; p < 2; ++p) {
    const int* sel = p ? sel_i2 : sel_i1;
    float* outp = out + (p ? 6094848 : 196608);
    gather_kernel<<<dim3(60, 128), 128, 0, stream>>>(sel, kn, image_feats, qn, xs, 60, 197);
    gemm_bt<EPI_QSCALE><<<dim3(6, 60), 256, 0, stream>>>(qn, WqT, bq, nullptr, Qb, 7680, 768, 768);
    attn_kernel<64, 224, 60, 197, false><<<dim3(12, 128), 256, 0, stream>>>(Qb, Kb, Vb, nullptr, qn);
    gemm_bt<EPI_RES_FADD><<<dim3(6, 60), 256, 0, stream>>>(qn, WoT, bo, xs, x1, 7680, 768, 768);
    ln_rows<<<7680 / 4, 256, 0, stream>>>(x1, ln2_g, ln2_b, Qb);
    gemm_bt<EPI_GELU><<<dim3(24, 60), 256, 0, stream>>>(Qb, W1T, b1, nullptr, gb, 7680, 3072, 768);
    gemm_bt<EPI_RES_OUT><<<dim3(6, 60), 256, 0, stream>>>(gb, W2T, b2, x1, outp, 7680, 768, 3072);
  }

  // ---- text modality ----
  ln_rows<<<8192 / 4, 256, 0, stream>>>(text_feats, ln1_g, ln1_b, kn);
  gemm_bt<EPI_PLAIN><<<dim3(6, 64), 256, 0, stream>>>(kn, WkT, bk, nullptr, Kb, 8192, 768, 768);
  gemm_bt<EPI_PLAIN><<<dim3(6, 64), 256, 0, stream>>>(kn, WvT, bv, nullptr, Vb, 8192, 768, 768);
  for (int p = 0; p < 2; ++p) {
    const int* sel = p ? sel_t2 : sel_t1;
    float* outp = out + (p ? 13959168 : 11993088);
    gather_kernel<<<dim3(20, 128), 128, 0, stream>>>(sel, kn, text_feats, qn, xs, 20, 64);
    gemm_bt<EPI_QSCALE><<<dim3(6, 20), 256, 0, stream>>>(qn, WqT, bq, nullptr, Qb, 2560, 768, 768);
    attn_kernel<32, 64, 20, 64, true><<<dim3(12, 128), 256, 0, stream>>>(Qb, Kb, Vb, tokens, qn);
    gemm_bt<EPI_RES_FADD><<<dim3(6, 20), 256, 0, stream>>>(qn, WoT, bo, xs, x1, 2560, 768, 768);
    ln_rows<<<2560 / 4, 256, 0, stream>>>(x1, ln2_g, ln2_b, Qb);
    gemm_bt<EPI_GELU><<<dim3(24, 20), 256, 0, stream>>>(Qb, W1T, b1, nullptr, gb, 2560, 3072, 768);
    gemm_bt<EPI_RES_OUT><<<dim3(6, 20), 256, 0, stream>>>(gb, W2T, b2, x1, outp, 2560, 768, 3072);
  }
}

// Round 3
// 881.159 us; speedup vs baseline: 1.4361x; 1.4361x over previous
//
#include <hip/hip_runtime.h>

typedef unsigned short u16;
typedef __bf16 bf16x8 __attribute__((ext_vector_type(8)));
typedef float f32x4 __attribute__((ext_vector_type(4)));

__device__ __forceinline__ float b2f(u16 u) { return __builtin_bit_cast(float, (unsigned)u << 16); }
__device__ __forceinline__ u16 f2b(float f) {
  unsigned x = __builtin_bit_cast(unsigned, f);
  x += 0x7fffu + ((x >> 16) & 1u);
  return (u16)(x >> 16);
}

__device__ __forceinline__ void gload16(const u16* g, u16* l) {
  auto gp = (__attribute__((address_space(1))) void*)(void*)const_cast<u16*>(g);
  auto lp = (__attribute__((address_space(3))) void*)(void*)l;
  __builtin_amdgcn_global_load_lds(gp, lp, 16, 0, 0);
}

__device__ __forceinline__ f32x4 mfma16(bf16x8 a, bf16x8 b, f32x4 c) {
  return __builtin_amdgcn_mfma_f32_16x16x32_bf16(a, b, c, 0, 0, 0);
}

// ---------------- weight transpose (R x C) f32 -> (C x R) bf16 ----------------
__global__ __launch_bounds__(256) void transpose_k(const float* __restrict__ in, u16* __restrict__ out,
                                                   int R, int C) {
  __shared__ float tile[32][33];
  const int bx = blockIdx.x * 32, by = blockIdx.y * 32;
  const int x = threadIdx.x;
  for (int yy = threadIdx.y; yy < 32; yy += 8) tile[yy][x] = in[(size_t)(by + yy) * C + bx + x];
  __syncthreads();
  for (int yy = threadIdx.y; yy < 32; yy += 8) out[(size_t)(bx + yy) * R + by + x] = f2b(tile[x][yy]);
}

// ---------------- BN on row 0 of each batch (f32 -> f32) ----------------
__global__ __launch_bounds__(256) void bn_kernel(const float* __restrict__ feats, int Lrow,
                                                 const float* g, const float* b, const float* m, const float* v,
                                                 float* __restrict__ out) {
  const int bb = blockIdx.x;
  const float* row = feats + (size_t)bb * Lrow * 768;
  for (int d = threadIdx.x; d < 768; d += 256) {
    float x = row[d];
    out[bb * 768 + d] = (x - m[d]) * (1.0f / sqrtf(v[d] + 1e-5f)) * g[d] + b[d];
  }
}

// ---------------- stable top-k selection (rank-based) ----------------
// sel layout: [2][128][Lq] (part, batch, slot); slot 0 = CLS(0)
__global__ __launch_bounds__(256) void topk_sel(const float* __restrict__ score, int L, int Ksel,
                                                int* __restrict__ sel, int Lq) {
  __shared__ float s[256];
  const int b = blockIdx.x;
  const int stride2 = 128 * Lq;
  for (int i = threadIdx.x; i < L; i += 256) {
    float v = score[b * L + i];
    s[i] = (i == 0) ? 0.0f : v;
  }
  __syncthreads();
  for (int i = threadIdx.x; i < L; i += 256) {
    float si = s[i];
    int rank = 0;
    for (int j = 0; j < L; ++j) {
      float sj = s[j];
      rank += (sj > si) || (sj == si && j < i);
    }
    if (rank < Ksel) sel[b * Lq + rank + 1] = i;
    else if (rank < 2 * Ksel) sel[stride2 + b * Lq + (rank - Ksel) + 1] = i;
  }
  if (threadIdx.x == 0) { sel[b * Lq] = 0; sel[stride2 + b * Lq] = 0; }
}

// ---------------- LayerNorm (f32 in -> bf16 out), one wave per 768-row ----------------
__global__ __launch_bounds__(256) void ln_rows(const float* __restrict__ x, const float* g, const float* b,
                                               u16* __restrict__ out) {
  const int row = blockIdx.x * 4 + (threadIdx.x >> 6);
  const int l = threadIdx.x & 63;
  const float* xr = x + (size_t)row * 768;
  float v[12]; float s = 0.f;
#pragma unroll
  for (int i = 0; i < 12; ++i) { v[i] = xr[l + i * 64]; s += v[i]; }
  for (int d = 1; d < 64; d <<= 1) s += __shfl_xor(s, d);
  const float mu = s * (1.0f / 768.0f);
  float q = 0.f;
#pragma unroll
  for (int i = 0; i < 12; ++i) { float t = v[i] - mu; q += t * t; }
  for (int d = 1; d < 64; d <<= 1) q += __shfl_xor(q, d);
  const float rs = 1.0f / sqrtf(q * (1.0f / 768.0f) + 1e-5f);
#pragma unroll
  for (int i = 0; i < 12; ++i) {
    int c = l + i * 64;
    out[(size_t)row * 768 + c] = f2b((v[i] - mu) * rs * g[c] + b[c]);
  }
}

// ---------------- gather both parts: qn bf16 from kn, xs f32 from feats ----------------
__global__ __launch_bounds__(128) void gather_kernel(const int* __restrict__ sel, const u16* __restrict__ kn,
                                                     const float* __restrict__ feats, u16* __restrict__ qn,
                                                     float* __restrict__ xs, int Lq, int Lsrc) {
  const int q = blockIdx.x, by = blockIdx.y;
  const int p = by >> 7, b = by & 127;
  const int row = (p * 128 + b) * Lq + q;
  const int src = sel[row];
  const uint4* sq = (const uint4*)(kn + ((size_t)b * Lsrc + src) * 768);
  uint4* dq = (uint4*)(qn + (size_t)row * 768);
  for (int c = threadIdx.x; c < 96; c += 128) dq[c] = sq[c];
  const float4* sx = (const float4*)(feats + ((size_t)b * Lsrc + src) * 768);
  float4* dx = (float4*)(xs + (size_t)row * 768);
  for (int c = threadIdx.x; c < 192; c += 128) dx[c] = sx[c];
}

// ---------------- GEMM: C = A(MxK) * Bt(NxK)^T, fused epilogues ----------------
enum { EPI_PLAIN = 0, EPI_QSCALE = 1, EPI_GELU = 2, EPI_RES_FADD = 3, EPI_RES_OUT = 4 };

template <int EPI>
__global__ __launch_bounds__(256) void gemm_bt(const u16* __restrict__ A, const u16* __restrict__ Bt,
                                               const float* __restrict__ bias, const float* __restrict__ res,
                                               void* __restrict__ outp, int M, int N, int K) {
  __shared__ alignas(16) u16 As[128 * 32];
  __shared__ alignas(16) u16 Bs[128 * 32];
  const int tid = threadIdx.x, l = tid & 63, w = tid >> 6;
  const int m0 = blockIdx.y * 128, n0 = blockIdx.x * 128;
  const int wm = (w & 1) * 64, wn = (w >> 1) * 64;
  f32x4 acc[4][4] = {};
  const int sm = tid >> 2, sk = (tid & 3) * 8;
  const u16* aG = A + (size_t)(m0 + sm) * K + sk;
  const u16* bG = Bt + (size_t)(n0 + sm) * K + sk;
  const size_t rowK64 = (size_t)64 * K;
  for (int k0 = 0; k0 < K; k0 += 32) {
    gload16(aG + k0, &As[tid * 8]);
    gload16(aG + k0 + rowK64, &As[tid * 8 + 2048]);
    gload16(bG + k0, &Bs[tid * 8]);
    gload16(bG + k0 + rowK64, &Bs[tid * 8 + 2048]);
    __syncthreads();
    bf16x8 af[4], bfr[4];
#pragma unroll
    for (int i = 0; i < 4; ++i) af[i] = *(const bf16x8*)&As[(wm + i * 16 + (l & 15)) * 32 + (l >> 4) * 8];
#pragma unroll
    for (int i = 0; i < 4; ++i) bfr[i] = *(const bf16x8*)&Bs[(wn + i * 16 + (l & 15)) * 32 + (l >> 4) * 8];
#pragma unroll
    for (int mi = 0; mi < 4; ++mi)
#pragma unroll
      for (int ni = 0; ni < 4; ++ni) acc[mi][ni] = mfma16(af[mi], bfr[ni], acc[mi][ni]);
    __syncthreads();
  }
  const int r4 = (l >> 4) * 4, c16 = l & 15;
#pragma unroll
  for (int mi = 0; mi < 4; ++mi) {
#pragma unroll
    for (int ni = 0; ni < 4; ++ni) {
      const int gn = n0 + wn + ni * 16 + c16;
      const float bia = bias[gn];
#pragma unroll
      for (int j = 0; j < 4; ++j) {
        const int gm = m0 + wm + mi * 16 + r4 + j;
        const size_t off = (size_t)gm * N + gn;
        float v = acc[mi][ni][j] + bia;
        if constexpr (EPI == EPI_QSCALE) {
          ((u16*)outp)[off] = f2b(v * 0.125f);
        } else if constexpr (EPI == EPI_GELU) {
          ((u16*)outp)[off] = f2b(0.5f * v * (1.0f + erff(v * 0.70710678118654752f)));
        } else if constexpr (EPI == EPI_RES_FADD || EPI == EPI_RES_OUT) {
          ((float*)outp)[off] = v + res[off];
        } else {
          ((u16*)outp)[off] = f2b(v);
        }
      }
    }
  }
}

// ---------------- attention v2: one WG per (head, part*batch) ----------------
// LDS: Qs swizzled [LQP][64]; KV time-shared: K-phase [LKP][64] swizzled,
// V-phase [64][LKS] transposed; Ss bf16 [LQP][LKS], softmax in-place (per-row warp ownership).
template <int LQP, int LKP, int LQ, int LK, bool MASK>
__global__ __launch_bounds__(256) void attn2(const u16* __restrict__ Q, const u16* __restrict__ Kb,
                                             const u16* __restrict__ Vb, const int* __restrict__ toks,
                                             u16* __restrict__ O) {
  constexpr int LKS = LKP + 8;  // pad: 2*LKS bytes/row -> banks%32 in {20,4}: 2-way (free)
  const int h = blockIdx.x, by = blockIdx.y;
  const int p = by & 1, bb = by >> 1;  // adjacent blocks share (bb,h) K/V -> L2 reuse
  const int tid = threadIdx.x, l = tid & 63, w = tid >> 6;
  const size_t qrow0 = (size_t)(p * 128 + bb) * LQ;
  const u16* Qg = Q + qrow0 * 768 + h * 64;
  const u16* Kg = Kb + (size_t)bb * LK * 768 + h * 64;
  const u16* Vg = Vb + (size_t)bb * LK * 768 + h * 64;

  __shared__ alignas(16) u16 Qs[LQP * 64];
  __shared__ alignas(16) u16 KV[64 * LKS];
  __shared__ alignas(16) u16 Ss[LQP * LKS];
  __shared__ int tokLds[MASK ? LKP : 1];

  // stage Q,K via global_load_lds with pre-swizzled global source (linear LDS dest)
  for (int s = tid; s < LQP * 8; s += 256) {
    int row = s >> 3, d8 = (s & 7) ^ (row & 7);
    int gr = row < LQ ? row : LQ - 1;  // clamp: finite garbage rows, never stored
    gload16(Qg + (size_t)gr * 768 + d8 * 8, &Qs[s * 8]);
  }
  for (int s = tid; s < LKP * 8; s += 256) {
    int row = s >> 3, d8 = (s & 7) ^ (row & 7);
    int gr = row < LK ? row : LK - 1;  // cols >= LK masked to 0 in softmax
    gload16(Kg + (size_t)gr * 768 + d8 * 8, &KV[s * 8]);
  }
  if (MASK)
    for (int c = tid; c < LKP; c += 256) tokLds[c] = (c < LK) ? toks[bb * LK + c] : 1;
  __syncthreads();

  // QK^T -> Ss (bf16)
  for (int nt = w; nt < LKP / 16; nt += 4) {
    const int brow = nt * 16 + (l & 15);
#pragma unroll
    for (int mt = 0; mt < LQP / 16; ++mt) {
      const int arow = mt * 16 + (l & 15);
      f32x4 a_ = {0.f, 0.f, 0.f, 0.f};
#pragma unroll
      for (int kk = 0; kk < 2; ++kk) {
        bf16x8 av = *(const bf16x8*)&Qs[arow * 64 + (((kk * 4 + (l >> 4)) ^ (arow & 7)) << 3)];
        bf16x8 bv = *(const bf16x8*)&KV[brow * 64 + (((kk * 4 + (l >> 4)) ^ (brow & 7)) << 3)];
        a_ = mfma16(av, bv, a_);
      }
      const int r0 = mt * 16 + (l >> 4) * 4, cc = nt * 16 + (l & 15);
#pragma unroll
      for (int j = 0; j < 4; ++j) Ss[(r0 + j) * LKS + cc] = f2b(a_[j]);
    }
  }
  __syncthreads();  // KV (K-data) dead; Ss complete

  // stage V transposed into KV (overlaps softmax VALU)
  {
    const int kcol = tid & 31, d8 = tid >> 5;
#pragma unroll
    for (int kb = 0; kb < LKP / 32; ++kb) {
      const int k = kb * 32 + kcol;
      alignas(16) u16 tmp[8] = {0, 0, 0, 0, 0, 0, 0, 0};
      if (k < LK) *(uint4*)tmp = *(const uint4*)(Vg + (size_t)k * 768 + d8 * 8);
#pragma unroll
      for (int j = 0; j < 8; ++j) KV[(d8 * 8 + j) * LKS + k] = tmp[j];
    }
  }
  // softmax in-place on Ss rows (each warp owns its rows)
  constexpr int NCH = (LKP + 63) / 64;
  for (int r = w; r < LQ; r += 4) {
    float sv[NCH];
    float mx = -INFINITY;
#pragma unroll
    for (int i = 0; i < NCH; ++i) {
      int c = l + (i << 6);
      float s = -INFINITY;
      if (c < LK) {
        s = b2f(Ss[r * LKS + c]);
        if (MASK && tokLds[c] == 0) s = -1e9f;
      }
      sv[i] = s;
      mx = fmaxf(mx, s);
    }
    for (int d = 1; d < 64; d <<= 1) mx = fmaxf(mx, __shfl_xor(mx, d));
    float sum = 0.f;
#pragma unroll
    for (int i = 0; i < NCH; ++i) { float e = __expf(sv[i] - mx); sv[i] = e; sum += e; }
    for (int d = 1; d < 64; d <<= 1) sum += __shfl_xor(sum, d);
    const float inv = 1.0f / sum;
#pragma unroll
    for (int i = 0; i < NCH; ++i) {
      int c = l + (i << 6);
      if (c < LKP) Ss[r * LKS + c] = f2b(sv[i] * inv);
    }
  }
  __syncthreads();

  // P*V -> O
  for (int mt = w; mt < LQP / 16; mt += 4) {
    const int arow = mt * 16 + (l & 15);
#pragma unroll
    for (int nt = 0; nt < 4; ++nt) {
      f32x4 a_ = {0.f, 0.f, 0.f, 0.f};
#pragma unroll
      for (int kk = 0; kk < LKP; kk += 32) {
        bf16x8 av = *(const bf16x8*)&Ss[arow * LKS + kk + (l >> 4) * 8];
        bf16x8 bv = *(const bf16x8*)&KV[(nt * 16 + (l & 15)) * LKS + kk + (l >> 4) * 8];
        a_ = mfma16(av, bv, a_);
      }
      const int r0 = mt * 16 + (l >> 4) * 4, c16 = l & 15;
#pragma unroll
      for (int j = 0; j < 4; ++j) {
        int r = r0 + j;
        if (r < LQ) O[(qrow0 + r) * 768 + h * 64 + nt * 16 + c16] = f2b(a_[j]);
      }
    }
  }
}

// ---------------------------------------------------------------
extern "C" void kernel_launch(void* const* d_in, const int* in_sizes, int n_in,
                              void* d_out, int out_size, void* d_ws, size_t ws_size,
                              hipStream_t stream) {
  (void)in_sizes; (void)n_in; (void)out_size; (void)ws_size;
  const float* image_feats = (const float*)d_in[0];
  const float* image_att = (const float*)d_in[1];
  const float* text_feats = (const float*)d_in[2];
  const float* text_att = (const float*)d_in[3];
  const int* tokens = (const int*)d_in[4];
  const float* bn_img_g = (const float*)d_in[5];
  const float* bn_img_b = (const float*)d_in[6];
  const float* bn_img_m = (const float*)d_in[7];
  const float* bn_img_v = (const float*)d_in[8];
  const float* bn_txt_g = (const float*)d_in[9];
  const float* bn_txt_b = (const float*)d_in[10];
  const float* bn_txt_m = (const float*)d_in[11];
  const float* bn_txt_v = (const float*)d_in[12];
  const float* ln1_g = (const float*)d_in[13];
  const float* ln1_b = (const float*)d_in[14];
  const float* ln2_g = (const float*)d_in[15];
  const float* ln2_b = (const float*)d_in[16];
  const float* Wq = (const float*)d_in[17];
  const float* Wk = (const float*)d_in[18];
  const float* Wv = (const float*)d_in[19];
  const float* Wo = (const float*)d_in[20];
  const float* bq = (const float*)d_in[21];
  const float* bk = (const float*)d_in[22];
  const float* bv = (const float*)d_in[23];
  const float* bo = (const float*)d_in[24];
  const float* W1 = (const float*)d_in[25];
  const float* b1 = (const float*)d_in[26];
  const float* W2 = (const float*)d_in[27];
  const float* b2 = (const float*)d_in[28];

  float* out = (float*)d_out;
  char* wsp = (char*)d_ws;
  size_t off = 0;
  auto alloc = [&](size_t bytes) -> void* {
    void* p = wsp + off;
    off += (bytes + 255) & ~(size_t)255;
    return p;
  };
  // weights
  u16* WqT = (u16*)alloc(768 * 768 * 2);
  u16* WkT = (u16*)alloc(768 * 768 * 2);
  u16* WvT = (u16*)alloc(768 * 768 * 2);
  u16* WoT = (u16*)alloc(768 * 768 * 2);
  u16* W1T = (u16*)alloc((size_t)768 * 3072 * 2);
  u16* W2T = (u16*)alloc((size_t)768 * 3072 * 2);
  // K/V pipelines (dead after attn; gb aliases this region)
  char* kvbase = (char*)(wsp + off);
  u16* kn_i = (u16*)alloc((size_t)25216 * 768 * 2);
  u16* Kb_i = (u16*)alloc((size_t)25216 * 768 * 2);
  u16* Vb_i = (u16*)alloc((size_t)25216 * 768 * 2);
  u16* kn_t = (u16*)alloc((size_t)8192 * 768 * 2);
  u16* Kb_t = (u16*)alloc((size_t)8192 * 768 * 2);
  u16* Vb_t = (u16*)alloc((size_t)8192 * 768 * 2);
  u16* gb = (u16*)kvbase;  // FF intermediate [20480 x 3072] bf16 = 126 MB <= 154 MB region
  // combined row space: rows 0..15359 image (p,b,60), 15360..20479 text (p,b,20)
  int* sel_i = (int*)alloc(2 * 128 * 60 * 4);
  int* sel_t = (int*)alloc(2 * 128 * 20 * 4);
  u16* qn = (u16*)alloc((size_t)20480 * 768 * 2);     // LN'd gathered rows; reused as att-out
  float* xs = (float*)alloc((size_t)20480 * 768 * 4); // residual x; becomes x1 = x+att in-place
  u16* Qb = (u16*)alloc((size_t)20480 * 768 * 2);     // Q proj; reused as h (LN2 out)

  const dim3 tb(32, 8);
  transpose_k<<<dim3(24, 24), tb, 0, stream>>>(Wq, WqT, 768, 768);
  transpose_k<<<dim3(24, 24), tb, 0, stream>>>(Wk, WkT, 768, 768);
  transpose_k<<<dim3(24, 24), tb, 0, stream>>>(Wv, WvT, 768, 768);
  transpose_k<<<dim3(24, 24), tb, 0, stream>>>(Wo, WoT, 768, 768);
  transpose_k<<<dim3(96, 24), tb, 0, stream>>>(W1, W1T, 768, 3072);
  transpose_k<<<dim3(24, 96), tb, 0, stream>>>(W2, W2T, 3072, 768);

  bn_kernel<<<128, 256, 0, stream>>>(image_feats, 197, bn_img_g, bn_img_b, bn_img_m, bn_img_v, out);
  bn_kernel<<<128, 256, 0, stream>>>(text_feats, 64, bn_txt_g, bn_txt_b, bn_txt_m, bn_txt_v, out + 98304);

  topk_sel<<<128, 256, 0, stream>>>(image_att, 197, 59, sel_i, 60);
  topk_sel<<<128, 256, 0, stream>>>(text_att, 64, 19, sel_t, 20);

  // shared K/V per modality
  ln_rows<<<25216 / 4, 256, 0, stream>>>(image_feats, ln1_g, ln1_b, kn_i);
  gemm_bt<EPI_PLAIN><<<dim3(6, 197), 256, 0, stream>>>(kn_i, WkT, bk, nullptr, Kb_i, 25216, 768, 768);
  gemm_bt<EPI_PLAIN><<<dim3(6, 197), 256, 0, stream>>>(kn_i, WvT, bv, nullptr, Vb_i, 25216, 768, 768);
  ln_rows<<<8192 / 4, 256, 0, stream>>>(text_feats, ln1_g, ln1_b, kn_t);
  gemm_bt<EPI_PLAIN><<<dim3(6, 64), 256, 0, stream>>>(kn_t, WkT, bk, nullptr, Kb_t, 8192, 768, 768);
  gemm_bt<EPI_PLAIN><<<dim3(6, 64), 256, 0, stream>>>(kn_t, WvT, bv, nullptr, Vb_t, 8192, 768, 768);

  // gather both parts of both modalities into the combined row space
  gather_kernel<<<dim3(60, 256), 128, 0, stream>>>(sel_i, kn_i, image_feats, qn, xs, 60, 197);
  gather_kernel<<<dim3(20, 256), 128, 0, stream>>>(sel_t, kn_t, text_feats, qn + (size_t)15360 * 768,
                                                   xs + (size_t)15360 * 768, 20, 64);

  // Q projection (combined, pre-scaled by 1/sqrt(64))
  gemm_bt<EPI_QSCALE><<<dim3(6, 160), 256, 0, stream>>>(qn, WqT, bq, nullptr, Qb, 20480, 768, 768);

  // attention (writes att-out into qn)
  attn2<64, 224, 60, 197, false><<<dim3(12, 256), 256, 0, stream>>>(Qb, Kb_i, Vb_i, nullptr, qn);
  attn2<32, 64, 20, 64, true><<<dim3(12, 256), 256, 0, stream>>>(Qb + (size_t)15360 * 768, Kb_t, Vb_t,
                                                                 tokens, qn + (size_t)15360 * 768);

  // x1 = xs + att@Wo + bo   (in-place on xs)
  gemm_bt<EPI_RES_FADD><<<dim3(6, 160), 256, 0, stream>>>(qn, WoT, bo, xs, xs, 20480, 768, 768);
  // h = LN2(x1)
  ln_rows<<<20480 / 4, 256, 0, stream>>>(xs, ln2_g, ln2_b, Qb);
  // gb = gelu(h@W1 + b1)
  gemm_bt<EPI_GELU><<<dim3(24, 160), 256, 0, stream>>>(Qb, W1T, b1, nullptr, gb, 20480, 3072, 768);
  // out = x1 + gb@W2 + b2  (combined rows map exactly onto out regions ip1|ip2|tp1|tp2)
  gemm_bt<EPI_RES_OUT><<<dim3(6, 160), 256, 0, stream>>>(gb, W2T, b2, xs, out + 196608, 20480, 768, 3072);
}

// Round 4
// 796.137 us; speedup vs baseline: 1.5895x; 1.1068x over previous
//
#include <hip/hip_runtime.h>

typedef unsigned short u16;
typedef __bf16 bf16x8 __attribute__((ext_vector_type(8)));
typedef float f32x4 __attribute__((ext_vector_type(4)));

__device__ __forceinline__ float b2f(u16 u) { return __builtin_bit_cast(float, (unsigned)u << 16); }
__device__ __forceinline__ u16 f2b(float f) {
  unsigned x = __builtin_bit_cast(unsigned, f);
  x += 0x7fffu + ((x >> 16) & 1u);
  return (u16)(x >> 16);
}

__device__ __forceinline__ void gload16(const u16* g, u16* l) {
  auto gp = (__attribute__((address_space(1))) void*)(void*)const_cast<u16*>(g);
  auto lp = (__attribute__((address_space(3))) void*)(void*)l;
  __builtin_amdgcn_global_load_lds(gp, lp, 16, 0, 0);
}

__device__ __forceinline__ f32x4 mfma16(bf16x8 a, bf16x8 b, f32x4 c) {
  return __builtin_amdgcn_mfma_f32_16x16x32_bf16(a, b, c, 0, 0, 0);
}

// overflow-stable tanh-form GELU (hardware v_exp_f32)
__device__ __forceinline__ float gelu_fast(float v) {
  float u = v * (0.7978845608028654f + 0.03567740813636141f * v * v);
  float e = __expf(2.0f * u);
  float th = 1.0f - 2.0f / (e + 1.0f);
  return 0.5f * v * (1.0f + th);
}

// ---------------- weight transpose (R x C) f32 -> (C x R) bf16 ----------------
__global__ __launch_bounds__(256) void transpose_k(const float* __restrict__ in, u16* __restrict__ out,
                                                   int R, int C) {
  __shared__ float tile[32][33];
  const int bx = blockIdx.x * 32, by = blockIdx.y * 32;
  const int x = threadIdx.x;
  for (int yy = threadIdx.y; yy < 32; yy += 8) tile[yy][x] = in[(size_t)(by + yy) * C + bx + x];
  __syncthreads();
  for (int yy = threadIdx.y; yy < 32; yy += 8) out[(size_t)(bx + yy) * R + by + x] = f2b(tile[x][yy]);
}

// ---------------- BN on row 0 of each batch (f32 -> f32) ----------------
__global__ __launch_bounds__(256) void bn_kernel(const float* __restrict__ feats, int Lrow,
                                                 const float* g, const float* b, const float* m, const float* v,
                                                 float* __restrict__ out) {
  const int bb = blockIdx.x;
  const float* row = feats + (size_t)bb * Lrow * 768;
  for (int d = threadIdx.x; d < 768; d += 256) {
    float x = row[d];
    out[bb * 768 + d] = (x - m[d]) * (1.0f / sqrtf(v[d] + 1e-5f)) * g[d] + b[d];
  }
}

// ---------------- stable top-k selection (rank-based) ----------------
// sel layout: [2][128][Lq] (part, batch, slot); slot 0 = CLS(0)
__global__ __launch_bounds__(256) void topk_sel(const float* __restrict__ score, int L, int Ksel,
                                                int* __restrict__ sel, int Lq) {
  __shared__ float s[256];
  const int b = blockIdx.x;
  const int stride2 = 128 * Lq;
  for (int i = threadIdx.x; i < L; i += 256) {
    float v = score[b * L + i];
    s[i] = (i == 0) ? 0.0f : v;
  }
  __syncthreads();
  for (int i = threadIdx.x; i < L; i += 256) {
    float si = s[i];
    int rank = 0;
    for (int j = 0; j < L; ++j) {
      float sj = s[j];
      rank += (sj > si) || (sj == si && j < i);
    }
    if (rank < Ksel) sel[b * Lq + rank + 1] = i;
    else if (rank < 2 * Ksel) sel[stride2 + b * Lq + (rank - Ksel) + 1] = i;
  }
  if (threadIdx.x == 0) { sel[b * Lq] = 0; sel[stride2 + b * Lq] = 0; }
}

// ---------------- LayerNorm (f32 in -> bf16 out), one wave per 768-row ----------------
__global__ __launch_bounds__(256) void ln_rows(const float* __restrict__ x, const float* g, const float* b,
                                               u16* __restrict__ out) {
  const int row = blockIdx.x * 4 + (threadIdx.x >> 6);
  const int l = threadIdx.x & 63;
  const float* xr = x + (size_t)row * 768;
  float v[12]; float s = 0.f;
#pragma unroll
  for (int i = 0; i < 12; ++i) { v[i] = xr[l + i * 64]; s += v[i]; }
  for (int d = 1; d < 64; d <<= 1) s += __shfl_xor(s, d);
  const float mu = s * (1.0f / 768.0f);
  float q = 0.f;
#pragma unroll
  for (int i = 0; i < 12; ++i) { float t = v[i] - mu; q += t * t; }
  for (int d = 1; d < 64; d <<= 1) q += __shfl_xor(q, d);
  const float rs = 1.0f / sqrtf(q * (1.0f / 768.0f) + 1e-5f);
#pragma unroll
  for (int i = 0; i < 12; ++i) {
    int c = l + i * 64;
    out[(size_t)row * 768 + c] = f2b((v[i] - mu) * rs * g[c] + b[c]);
  }
}

// ---------------- gather both parts: qn bf16 from kn, xs f32 from feats ----------------
__global__ __launch_bounds__(128) void gather_kernel(const int* __restrict__ sel, const u16* __restrict__ kn,
                                                     const float* __restrict__ feats, u16* __restrict__ qn,
                                                     float* __restrict__ xs, int Lq, int Lsrc) {
  const int q = blockIdx.x, by = blockIdx.y;
  const int p = by >> 7, b = by & 127;
  const int row = (p * 128 + b) * Lq + q;
  const int src = sel[row];
  const uint4* sq = (const uint4*)(kn + ((size_t)b * Lsrc + src) * 768);
  uint4* dq = (uint4*)(qn + (size_t)row * 768);
  for (int c = threadIdx.x; c < 96; c += 128) dq[c] = sq[c];
  const float4* sx = (const float4*)(feats + ((size_t)b * Lsrc + src) * 768);
  float4* dx = (float4*)(xs + (size_t)row * 768);
  for (int c = threadIdx.x; c < 192; c += 128) dx[c] = sx[c];
}

// ---------------- GEMM v2: BK=64, XOR-swizzled LDS, XCD-bijective block swizzle ----------------
enum { EPI_PLAIN = 0, EPI_QSCALE = 1, EPI_GELU = 2, EPI_RES_FADD = 3, EPI_RES_OUT = 4 };

template <int EPI>
__global__ __launch_bounds__(256) void gemm_bt(const u16* __restrict__ A, const u16* __restrict__ Bt,
                                               const float* __restrict__ bias, const float* __restrict__ res,
                                               void* __restrict__ outp, int M, int N, int K) {
  __shared__ alignas(16) u16 As[128 * 64];
  __shared__ alignas(16) u16 Bs[128 * 64];
  const int tid = threadIdx.x, l = tid & 63, w = tid >> 6;
  // bijective XCD swizzle (m204): contiguous tile chunk per XCD
  const int nwg = gridDim.x * gridDim.y;
  {
  }
  int lin = blockIdx.y * gridDim.x + blockIdx.x;
  const int q8 = nwg >> 3, r8 = nwg & 7;
  const int xcd = lin & 7, pos = lin >> 3;
  const int nl = (xcd < r8) ? (xcd * (q8 + 1) + pos) : (r8 * (q8 + 1) + (xcd - r8) * q8 + pos);
  const int m0 = (nl / gridDim.x) * 128, n0 = (nl % gridDim.x) * 128;
  const int wm = (w & 1) * 64, wn = (w >> 1) * 64;
  f32x4 acc[4][4] = {};
  // staging: LDS[row][t] = G[row][t ^ (row&7)] (16B chunks), LDS dest linear per wave
  for (int k0 = 0; k0 < K; k0 += 64) {
#pragma unroll
    for (int p = 0; p < 4; ++p) {
      const int s = p * 256 + tid;
      const int row = s >> 3, ch = (s & 7) ^ (row & 7);
      gload16(A + (size_t)(m0 + row) * K + k0 + ch * 8, &As[s * 8]);
    }
#pragma unroll
    for (int p = 0; p < 4; ++p) {
      const int s = p * 256 + tid;
      const int row = s >> 3, ch = (s & 7) ^ (row & 7);
      gload16(Bt + (size_t)(n0 + row) * K + k0 + ch * 8, &Bs[s * 8]);
    }
    __syncthreads();
#pragma unroll
    for (int kk = 0; kk < 2; ++kk) {
      bf16x8 af[4], bfr[4];
#pragma unroll
      for (int i = 0; i < 4; ++i) {
        const int arow = wm + i * 16 + (l & 15);
        af[i] = *(const bf16x8*)&As[arow * 64 + ((((kk * 4 + (l >> 4))) ^ (arow & 7)) << 3)];
        const int brow = wn + i * 16 + (l & 15);
        bfr[i] = *(const bf16x8*)&Bs[brow * 64 + ((((kk * 4 + (l >> 4))) ^ (brow & 7)) << 3)];
      }
#pragma unroll
      for (int mi = 0; mi < 4; ++mi)
#pragma unroll
        for (int ni = 0; ni < 4; ++ni) acc[mi][ni] = mfma16(af[mi], bfr[ni], acc[mi][ni]);
    }
    __syncthreads();
  }
  const int r4 = (l >> 4) * 4, c16 = l & 15;
#pragma unroll
  for (int mi = 0; mi < 4; ++mi) {
#pragma unroll
    for (int ni = 0; ni < 4; ++ni) {
      const int gn = n0 + wn + ni * 16 + c16;
      const float bia = bias[gn];
#pragma unroll
      for (int j = 0; j < 4; ++j) {
        const int gm = m0 + wm + mi * 16 + r4 + j;
        const size_t off = (size_t)gm * N + gn;
        float v = acc[mi][ni][j] + bia;
        if constexpr (EPI == EPI_QSCALE) {
          ((u16*)outp)[off] = f2b(v * 0.125f);
        } else if constexpr (EPI == EPI_GELU) {
          ((u16*)outp)[off] = f2b(gelu_fast(v));
        } else if constexpr (EPI == EPI_RES_FADD || EPI == EPI_RES_OUT) {
          ((float*)outp)[off] = v + res[off];
        } else {
          ((u16*)outp)[off] = f2b(v);
        }
      }
    }
  }
}

// ---------------- attention v2: one WG per (head, part*batch) ----------------
template <int LQP, int LKP, int LQ, int LK, bool MASK>
__global__ __launch_bounds__(256) void attn2(const u16* __restrict__ Q, const u16* __restrict__ Kb,
                                             const u16* __restrict__ Vb, const int* __restrict__ toks,
                                             u16* __restrict__ O) {
  constexpr int LKS = LKP + 8;  // pad: 2-way max (free)
  const int h = blockIdx.x, by = blockIdx.y;
  const int p = by & 1, bb = by >> 1;
  const int tid = threadIdx.x, l = tid & 63, w = tid >> 6;
  const size_t qrow0 = (size_t)(p * 128 + bb) * LQ;
  const u16* Qg = Q + qrow0 * 768 + h * 64;
  const u16* Kg = Kb + (size_t)bb * LK * 768 + h * 64;
  const u16* Vg = Vb + (size_t)bb * LK * 768 + h * 64;

  __shared__ alignas(16) u16 Qs[LQP * 64];
  __shared__ alignas(16) u16 KV[64 * LKS];
  __shared__ alignas(16) u16 Ss[LQP * LKS];
  __shared__ int tokLds[MASK ? LKP : 1];

  for (int s = tid; s < LQP * 8; s += 256) {
    int row = s >> 3, d8 = (s & 7) ^ (row & 7);
    int gr = row < LQ ? row : LQ - 1;
    gload16(Qg + (size_t)gr * 768 + d8 * 8, &Qs[s * 8]);
  }
  for (int s = tid; s < LKP * 8; s += 256) {
    int row = s >> 3, d8 = (s & 7) ^ (row & 7);
    int gr = row < LK ? row : LK - 1;
    gload16(Kg + (size_t)gr * 768 + d8 * 8, &KV[s * 8]);
  }
  if (MASK)
    for (int c = tid; c < LKP; c += 256) tokLds[c] = (c < LK) ? toks[bb * LK + c] : 1;
  __syncthreads();

  // QK^T -> Ss (bf16)
  for (int nt = w; nt < LKP / 16; nt += 4) {
    const int brow = nt * 16 + (l & 15);
#pragma unroll
    for (int mt = 0; mt < LQP / 16; ++mt) {
      const int arow = mt * 16 + (l & 15);
      f32x4 a_ = {0.f, 0.f, 0.f, 0.f};
#pragma unroll
      for (int kk = 0; kk < 2; ++kk) {
        bf16x8 av = *(const bf16x8*)&Qs[arow * 64 + (((kk * 4 + (l >> 4)) ^ (arow & 7)) << 3)];
        bf16x8 bv = *(const bf16x8*)&KV[brow * 64 + (((kk * 4 + (l >> 4)) ^ (brow & 7)) << 3)];
        a_ = mfma16(av, bv, a_);
      }
      const int r0 = mt * 16 + (l >> 4) * 4, cc = nt * 16 + (l & 15);
#pragma unroll
      for (int j = 0; j < 4; ++j) Ss[(r0 + j) * LKS + cc] = f2b(a_[j]);
    }
  }
  __syncthreads();

  // stage V transposed into KV (overlaps softmax VALU)
  {
    const int kcol = tid & 31, d8 = tid >> 5;
#pragma unroll
    for (int kb = 0; kb < LKP / 32; ++kb) {
      const int k = kb * 32 + kcol;
      alignas(16) u16 tmp[8] = {0, 0, 0, 0, 0, 0, 0, 0};
      if (k < LK) *(uint4*)tmp = *(const uint4*)(Vg + (size_t)k * 768 + d8 * 8);
#pragma unroll
      for (int j = 0; j < 8; ++j) KV[(d8 * 8 + j) * LKS + k] = tmp[j];
    }
  }
  // softmax in-place on Ss rows
  constexpr int NCH = (LKP + 63) / 64;
  for (int r = w; r < LQ; r += 4) {
    float sv[NCH];
    float mx = -INFINITY;
#pragma unroll
    for (int i = 0; i < NCH; ++i) {
      int c = l + (i << 6);
      float s = -INFINITY;
      if (c < LK) {
        s = b2f(Ss[r * LKS + c]);
        if (MASK && tokLds[c] == 0) s = -1e9f;
      }
      sv[i] = s;
      mx = fmaxf(mx, s);
    }
    for (int d = 1; d < 64; d <<= 1) mx = fmaxf(mx, __shfl_xor(mx, d));
    float sum = 0.f;
#pragma unroll
    for (int i = 0; i < NCH; ++i) { float e = __expf(sv[i] - mx); sv[i] = e; sum += e; }
    for (int d = 1; d < 64; d <<= 1) sum += __shfl_xor(sum, d);
    const float inv = 1.0f / sum;
#pragma unroll
    for (int i = 0; i < NCH; ++i) {
      int c = l + (i << 6);
      if (c < LKP) Ss[r * LKS + c] = f2b(sv[i] * inv);
    }
  }
  __syncthreads();

  // P*V -> O
  for (int mt = w; mt < LQP / 16; mt += 4) {
    const int arow = mt * 16 + (l & 15);
#pragma unroll
    for (int nt = 0; nt < 4; ++nt) {
      f32x4 a_ = {0.f, 0.f, 0.f, 0.f};
#pragma unroll
      for (int kk = 0; kk < LKP; kk += 32) {
        bf16x8 av = *(const bf16x8*)&Ss[arow * LKS + kk + (l >> 4) * 8];
        bf16x8 bv = *(const bf16x8*)&KV[(nt * 16 + (l & 15)) * LKS + kk + (l >> 4) * 8];
        a_ = mfma16(av, bv, a_);
      }
      const int r0 = mt * 16 + (l >> 4) * 4, c16 = l & 15;
#pragma unroll
      for (int j = 0; j < 4; ++j) {
        int r = r0 + j;
        if (r < LQ) O[(qrow0 + r) * 768 + h * 64 + nt * 16 + c16] = f2b(a_[j]);
      }
    }
  }
}

// ---------------------------------------------------------------
extern "C" void kernel_launch(void* const* d_in, const int* in_sizes, int n_in,
                              void* d_out, int out_size, void* d_ws, size_t ws_size,
                              hipStream_t stream) {
  (void)in_sizes; (void)n_in; (void)out_size; (void)ws_size;
  const float* image_feats = (const float*)d_in[0];
  const float* image_att = (const float*)d_in[1];
  const float* text_feats = (const float*)d_in[2];
  const float* text_att = (const float*)d_in[3];
  const int* tokens = (const int*)d_in[4];
  const float* bn_img_g = (const float*)d_in[5];
  const float* bn_img_b = (const float*)d_in[6];
  const float* bn_img_m = (const float*)d_in[7];
  const float* bn_img_v = (const float*)d_in[8];
  const float* bn_txt_g = (const float*)d_in[9];
  const float* bn_txt_b = (const float*)d_in[10];
  const float* bn_txt_m = (const float*)d_in[11];
  const float* bn_txt_v = (const float*)d_in[12];
  const float* ln1_g = (const float*)d_in[13];
  const float* ln1_b = (const float*)d_in[14];
  const float* ln2_g = (const float*)d_in[15];
  const float* ln2_b = (const float*)d_in[16];
  const float* Wq = (const float*)d_in[17];
  const float* Wk = (const float*)d_in[18];
  const float* Wv = (const float*)d_in[19];
  const float* Wo = (const float*)d_in[20];
  const float* bq = (const float*)d_in[21];
  const float* bk = (const float*)d_in[22];
  const float* bv = (const float*)d_in[23];
  const float* bo = (const float*)d_in[24];
  const float* W1 = (const float*)d_in[25];
  const float* b1 = (const float*)d_in[26];
  const float* W2 = (const float*)d_in[27];
  const float* b2 = (const float*)d_in[28];

  float* out = (float*)d_out;
  char* wsp = (char*)d_ws;
  size_t off = 0;
  auto alloc = [&](size_t bytes) -> void* {
    void* p = wsp + off;
    off += (bytes + 255) & ~(size_t)255;
    return p;
  };
  // weights
  u16* WqT = (u16*)alloc(768 * 768 * 2);
  u16* WkT = (u16*)alloc(768 * 768 * 2);
  u16* WvT = (u16*)alloc(768 * 768 * 2);
  u16* WoT = (u16*)alloc(768 * 768 * 2);
  u16* W1T = (u16*)alloc((size_t)768 * 3072 * 2);
  u16* W2T = (u16*)alloc((size_t)768 * 3072 * 2);
  // K/V pipelines (dead after attn; gb aliases this region)
  char* kvbase = (char*)(wsp + off);
  u16* kn_i = (u16*)alloc((size_t)25216 * 768 * 2);
  u16* Kb_i = (u16*)alloc((size_t)25216 * 768 * 2);
  u16* Vb_i = (u16*)alloc((size_t)25216 * 768 * 2);
  u16* kn_t = (u16*)alloc((size_t)8192 * 768 * 2);
  u16* Kb_t = (u16*)alloc((size_t)8192 * 768 * 2);
  u16* Vb_t = (u16*)alloc((size_t)8192 * 768 * 2);
  u16* gb = (u16*)kvbase;  // FF intermediate [20480 x 3072] bf16
  // combined row space: rows 0..15359 image (p,b,60), 15360..20479 text (p,b,20)
  int* sel_i = (int*)alloc(2 * 128 * 60 * 4);
  int* sel_t = (int*)alloc(2 * 128 * 20 * 4);
  u16* qn = (u16*)alloc((size_t)20480 * 768 * 2);
  float* xs = (float*)alloc((size_t)20480 * 768 * 4);
  u16* Qb = (u16*)alloc((size_t)20480 * 768 * 2);

  const dim3 tb(32, 8);
  transpose_k<<<dim3(24, 24), tb, 0, stream>>>(Wq, WqT, 768, 768);
  transpose_k<<<dim3(24, 24), tb, 0, stream>>>(Wk, WkT, 768, 768);
  transpose_k<<<dim3(24, 24), tb, 0, stream>>>(Wv, WvT, 768, 768);
  transpose_k<<<dim3(24, 24), tb, 0, stream>>>(Wo, WoT, 768, 768);
  transpose_k<<<dim3(96, 24), tb, 0, stream>>>(W1, W1T, 768, 3072);
  transpose_k<<<dim3(24, 96), tb, 0, stream>>>(W2, W2T, 3072, 768);

  bn_kernel<<<128, 256, 0, stream>>>(image_feats, 197, bn_img_g, bn_img_b, bn_img_m, bn_img_v, out);
  bn_kernel<<<128, 256, 0, stream>>>(text_feats, 64, bn_txt_g, bn_txt_b, bn_txt_m, bn_txt_v, out + 98304);

  topk_sel<<<128, 256, 0, stream>>>(image_att, 197, 59, sel_i, 60);
  topk_sel<<<128, 256, 0, stream>>>(text_att, 64, 19, sel_t, 20);

  // shared K/V per modality
  ln_rows<<<25216 / 4, 256, 0, stream>>>(image_feats, ln1_g, ln1_b, kn_i);
  gemm_bt<EPI_PLAIN><<<dim3(6, 197), 256, 0, stream>>>(kn_i, WkT, bk, nullptr, Kb_i, 25216, 768, 768);
  gemm_bt<EPI_PLAIN><<<dim3(6, 197), 256, 0, stream>>>(kn_i, WvT, bv, nullptr, Vb_i, 25216, 768, 768);
  ln_rows<<<8192 / 4, 256, 0, stream>>>(text_feats, ln1_g, ln1_b, kn_t);
  gemm_bt<EPI_PLAIN><<<dim3(6, 64), 256, 0, stream>>>(kn_t, WkT, bk, nullptr, Kb_t, 8192, 768, 768);
  gemm_bt<EPI_PLAIN><<<dim3(6, 64), 256, 0, stream>>>(kn_t, WvT, bv, nullptr, Vb_t, 8192, 768, 768);

  // gather both parts of both modalities into the combined row space
  gather_kernel<<<dim3(60, 256), 128, 0, stream>>>(sel_i, kn_i, image_feats, qn, xs, 60, 197);
  gather_kernel<<<dim3(20, 256), 128, 0, stream>>>(sel_t, kn_t, text_feats, qn + (size_t)15360 * 768,
                                                   xs + (size_t)15360 * 768, 20, 64);

  // Q projection (combined, pre-scaled by 1/sqrt(64))
  gemm_bt<EPI_QSCALE><<<dim3(6, 160), 256, 0, stream>>>(qn, WqT, bq, nullptr, Qb, 20480, 768, 768);

  // attention (writes att-out into qn)
  attn2<64, 224, 60, 197, false><<<dim3(12, 256), 256, 0, stream>>>(Qb, Kb_i, Vb_i, nullptr, qn);
  attn2<32, 64, 20, 64, true><<<dim3(12, 256), 256, 0, stream>>>(Qb + (size_t)15360 * 768, Kb_t, Vb_t,
                                                                 tokens, qn + (size_t)15360 * 768);

  // x1 = xs + att@Wo + bo   (in-place on xs)
  gemm_bt<EPI_RES_FADD><<<dim3(6, 160), 256, 0, stream>>>(qn, WoT, bo, xs, xs, 20480, 768, 768);
  // h = LN2(x1)
  ln_rows<<<20480 / 4, 256, 0, stream>>>(xs, ln2_g, ln2_b, Qb);
  // gb = gelu(h@W1 + b1)
  gemm_bt<EPI_GELU><<<dim3(24, 160), 256, 0, stream>>>(Qb, W1T, b1, nullptr, gb, 20480, 3072, 768);
  // out = x1 + gb@W2 + b2
  gemm_bt<EPI_RES_OUT><<<dim3(6, 160), 256, 0, stream>>>(gb, W2T, b2, xs, out + 196608, 20480, 768, 3072);
}

// Round 5
// 755.487 us; speedup vs baseline: 1.6750x; 1.0538x over previous
//
#include <hip/hip_runtime.h>

typedef unsigned short u16;
typedef __bf16 bf16x8 __attribute__((ext_vector_type(8)));
typedef float f32x4 __attribute__((ext_vector_type(4)));

__device__ __forceinline__ float b2f(u16 u) { return __builtin_bit_cast(float, (unsigned)u << 16); }
__device__ __forceinline__ u16 f2b(float f) {
  unsigned x = __builtin_bit_cast(unsigned, f);
  x += 0x7fffu + ((x >> 16) & 1u);
  return (u16)(x >> 16);
}

__device__ __forceinline__ void gload16(const u16* g, u16* l) {
  auto gp = (__attribute__((address_space(1))) void*)(void*)const_cast<u16*>(g);
  auto lp = (__attribute__((address_space(3))) void*)(void*)l;
  __builtin_amdgcn_global_load_lds(gp, lp, 16, 0, 0);
}

__device__ __forceinline__ f32x4 mfma16(bf16x8 a, bf16x8 b, f32x4 c) {
  return __builtin_amdgcn_mfma_f32_16x16x32_bf16(a, b, c, 0, 0, 0);
}

// overflow-stable tanh-form GELU (hardware v_exp_f32)
__device__ __forceinline__ float gelu_fast(float v) {
  float u = v * (0.7978845608028654f + 0.03567740813636141f * v * v);
  float e = __expf(2.0f * u);
  float th = 1.0f - 2.0f / (e + 1.0f);
  return 0.5f * v * (1.0f + th);
}

// ---------------- weight transpose (R x C) f32 -> (C x R) bf16 ----------------
__global__ __launch_bounds__(256) void transpose_k(const float* __restrict__ in, u16* __restrict__ out,
                                                   int R, int C) {
  __shared__ float tile[32][33];
  const int bx = blockIdx.x * 32, by = blockIdx.y * 32;
  const int x = threadIdx.x;
  for (int yy = threadIdx.y; yy < 32; yy += 8) tile[yy][x] = in[(size_t)(by + yy) * C + bx + x];
  __syncthreads();
  for (int yy = threadIdx.y; yy < 32; yy += 8) out[(size_t)(bx + yy) * R + by + x] = f2b(tile[x][yy]);
}

// ---------------- BN on row 0 of each batch (f32 -> f32) ----------------
__global__ __launch_bounds__(256) void bn_kernel(const float* __restrict__ feats, int Lrow,
                                                 const float* g, const float* b, const float* m, const float* v,
                                                 float* __restrict__ out) {
  const int bb = blockIdx.x;
  const float* row = feats + (size_t)bb * Lrow * 768;
  for (int d = threadIdx.x; d < 768; d += 256) {
    float x = row[d];
    out[bb * 768 + d] = (x - m[d]) * (1.0f / sqrtf(v[d] + 1e-5f)) * g[d] + b[d];
  }
}

// ---------------- stable top-k selection (rank-based) ----------------
__global__ __launch_bounds__(256) void topk_sel(const float* __restrict__ score, int L, int Ksel,
                                                int* __restrict__ sel, int Lq) {
  __shared__ float s[256];
  const int b = blockIdx.x;
  const int stride2 = 128 * Lq;
  for (int i = threadIdx.x; i < L; i += 256) {
    float v = score[b * L + i];
    s[i] = (i == 0) ? 0.0f : v;
  }
  __syncthreads();
  for (int i = threadIdx.x; i < L; i += 256) {
    float si = s[i];
    int rank = 0;
    for (int j = 0; j < L; ++j) {
      float sj = s[j];
      rank += (sj > si) || (sj == si && j < i);
    }
    if (rank < Ksel) sel[b * Lq + rank + 1] = i;
    else if (rank < 2 * Ksel) sel[stride2 + b * Lq + (rank - Ksel) + 1] = i;
  }
  if (threadIdx.x == 0) { sel[b * Lq] = 0; sel[stride2 + b * Lq] = 0; }
}

// ---------------- LayerNorm (f32 in -> bf16 out), one wave per 768-row ----------------
__global__ __launch_bounds__(256) void ln_rows(const float* __restrict__ x, const float* g, const float* b,
                                               u16* __restrict__ out) {
  const int row = blockIdx.x * 4 + (threadIdx.x >> 6);
  const int l = threadIdx.x & 63;
  const float* xr = x + (size_t)row * 768;
  float v[12]; float s = 0.f;
#pragma unroll
  for (int i = 0; i < 12; ++i) { v[i] = xr[l + i * 64]; s += v[i]; }
  for (int d = 1; d < 64; d <<= 1) s += __shfl_xor(s, d);
  const float mu = s * (1.0f / 768.0f);
  float q = 0.f;
#pragma unroll
  for (int i = 0; i < 12; ++i) { float t = v[i] - mu; q += t * t; }
  for (int d = 1; d < 64; d <<= 1) q += __shfl_xor(q, d);
  const float rs = 1.0f / sqrtf(q * (1.0f / 768.0f) + 1e-5f);
#pragma unroll
  for (int i = 0; i < 12; ++i) {
    int c = l + i * 64;
    out[(size_t)row * 768 + c] = f2b((v[i] - mu) * rs * g[c] + b[c]);
  }
}

// ---------------- gather both parts: qn bf16 from kn, xs f32 from feats ----------------
__global__ __launch_bounds__(128) void gather_kernel(const int* __restrict__ sel, const u16* __restrict__ kn,
                                                     const float* __restrict__ feats, u16* __restrict__ qn,
                                                     float* __restrict__ xs, int Lq, int Lsrc) {
  const int q = blockIdx.x, by = blockIdx.y;
  const int p = by >> 7, b = by & 127;
  const int row = (p * 128 + b) * Lq + q;
  const int src = sel[row];
  const uint4* sq = (const uint4*)(kn + ((size_t)b * Lsrc + src) * 768);
  uint4* dq = (uint4*)(qn + (size_t)row * 768);
  for (int c = threadIdx.x; c < 96; c += 128) dq[c] = sq[c];
  const float4* sx = (const float4*)(feats + ((size_t)b * Lsrc + src) * 768);
  float4* dx = (float4*)(xs + (size_t)row * 768);
  for (int c = threadIdx.x; c < 192; c += 128) dx[c] = sx[c];
}

// ---------------- GEMM v3: BK=64 swizzled LDS, 2-phase dbuf pipeline (counted vmcnt) ----------------
enum { EPI_PLAIN = 0, EPI_QSCALE = 1, EPI_GELU = 2, EPI_RES_FADD = 3, EPI_RES_OUT = 4 };

template <int EPI>
__global__ __launch_bounds__(256) void gemm_bt(const u16* __restrict__ A, const u16* __restrict__ Bt,
                                               const float* __restrict__ bias, const float* __restrict__ res,
                                               void* __restrict__ outp, int M, int N, int K) {
  __shared__ alignas(16) u16 As[2][128 * 64];
  __shared__ alignas(16) u16 Bs[2][128 * 64];
  const int tid = threadIdx.x, l = tid & 63, w = tid >> 6;
  // bijective XCD swizzle (m204)
  const int nwg = gridDim.x * gridDim.y;
  int lin = blockIdx.y * gridDim.x + blockIdx.x;
  const int q8 = nwg >> 3, r8 = nwg & 7;
  const int xcd = lin & 7, pos = lin >> 3;
  const int nl = (xcd < r8) ? (xcd * (q8 + 1) + pos) : (r8 * (q8 + 1) + (xcd - r8) * q8 + pos);
  const int m0 = (nl / gridDim.x) * 128, n0 = (nl % gridDim.x) * 128;
  const int wm = (w & 1) * 64, wn = (w >> 1) * 64;
  f32x4 acc[4][4] = {};

  auto STAGE = [&](int buf, int k0) {
#pragma unroll
    for (int p = 0; p < 4; ++p) {
      const int s = p * 256 + tid;
      const int row = s >> 3, ch = (s & 7) ^ (row & 7);
      gload16(A + (size_t)(m0 + row) * K + k0 + ch * 8, &As[buf][s * 8]);
      gload16(Bt + (size_t)(n0 + row) * K + k0 + ch * 8, &Bs[buf][s * 8]);
    }
  };
  auto COMPUTE = [&](int buf) {
#pragma unroll
    for (int kk = 0; kk < 2; ++kk) {
      bf16x8 af[4], bfr[4];
#pragma unroll
      for (int i = 0; i < 4; ++i) {
        const int arow = wm + i * 16 + (l & 15);
        af[i] = *(const bf16x8*)&As[buf][arow * 64 + ((((kk * 4 + (l >> 4))) ^ (arow & 7)) << 3)];
        const int brow = wn + i * 16 + (l & 15);
        bfr[i] = *(const bf16x8*)&Bs[buf][brow * 64 + ((((kk * 4 + (l >> 4))) ^ (brow & 7)) << 3)];
      }
#pragma unroll
      for (int mi = 0; mi < 4; ++mi)
#pragma unroll
        for (int ni = 0; ni < 4; ++ni) acc[mi][ni] = mfma16(af[mi], bfr[ni], acc[mi][ni]);
    }
  };

  const int NT = K >> 6;
  STAGE(0, 0);
  int cur = 0;
  for (int t = 0; t < NT - 1; ++t) {
    STAGE(cur ^ 1, (t + 1) << 6);                   // prefetch next tile (8 loads/wave in flight)
    asm volatile("s_waitcnt vmcnt(8)" ::: "memory");  // tile t's 8 loads complete (counted, not 0)
    __builtin_amdgcn_sched_barrier(0);
    __builtin_amdgcn_s_barrier();                   // all waves' shares visible
    COMPUTE(cur);
    __builtin_amdgcn_s_barrier();                   // done reading buf[cur] before t+1 overwrites it
    cur ^= 1;
  }
  asm volatile("s_waitcnt vmcnt(0)" ::: "memory");
  __builtin_amdgcn_sched_barrier(0);
  __builtin_amdgcn_s_barrier();
  COMPUTE(cur);

  const int r4 = (l >> 4) * 4, c16 = l & 15;
#pragma unroll
  for (int mi = 0; mi < 4; ++mi) {
#pragma unroll
    for (int ni = 0; ni < 4; ++ni) {
      const int gn = n0 + wn + ni * 16 + c16;
      const float bia = bias[gn];
#pragma unroll
      for (int j = 0; j < 4; ++j) {
        const int gm = m0 + wm + mi * 16 + r4 + j;
        const size_t off = (size_t)gm * N + gn;
        float v = acc[mi][ni][j] + bia;
        if constexpr (EPI == EPI_QSCALE) {
          ((u16*)outp)[off] = f2b(v * 0.125f);
        } else if constexpr (EPI == EPI_GELU) {
          ((u16*)outp)[off] = f2b(gelu_fast(v));
        } else if constexpr (EPI == EPI_RES_FADD || EPI == EPI_RES_OUT) {
          ((float*)outp)[off] = v + res[off];
        } else {
          ((u16*)outp)[off] = f2b(v);
        }
      }
    }
  }
}

// ---------------- attention v2: one WG per (head, part*batch) ----------------
template <int LQP, int LKP, int LQ, int LK, bool MASK>
__global__ __launch_bounds__(256) void attn2(const u16* __restrict__ Q, const u16* __restrict__ Kb,
                                             const u16* __restrict__ Vb, const int* __restrict__ toks,
                                             u16* __restrict__ O) {
  constexpr int LKS = LKP + 8;  // pad: 2-way max (free)
  const int h = blockIdx.x, by = blockIdx.y;
  const int p = by & 1, bb = by >> 1;
  const int tid = threadIdx.x, l = tid & 63, w = tid >> 6;
  const size_t qrow0 = (size_t)(p * 128 + bb) * LQ;
  const u16* Qg = Q + qrow0 * 768 + h * 64;
  const u16* Kg = Kb + (size_t)bb * LK * 768 + h * 64;
  const u16* Vg = Vb + (size_t)bb * LK * 768 + h * 64;

  __shared__ alignas(16) u16 Qs[LQP * 64];
  __shared__ alignas(16) u16 KV[64 * LKS];
  __shared__ alignas(16) u16 Ss[LQP * LKS];
  __shared__ int tokLds[MASK ? LKP : 1];

  for (int s = tid; s < LQP * 8; s += 256) {
    int row = s >> 3, d8 = (s & 7) ^ (row & 7);
    int gr = row < LQ ? row : LQ - 1;
    gload16(Qg + (size_t)gr * 768 + d8 * 8, &Qs[s * 8]);
  }
  for (int s = tid; s < LKP * 8; s += 256) {
    int row = s >> 3, d8 = (s & 7) ^ (row & 7);
    int gr = row < LK ? row : LK - 1;
    gload16(Kg + (size_t)gr * 768 + d8 * 8, &KV[s * 8]);
  }
  if (MASK)
    for (int c = tid; c < LKP; c += 256) tokLds[c] = (c < LK) ? toks[bb * LK + c] : 1;
  __syncthreads();

  // QK^T -> Ss (bf16)
  for (int nt = w; nt < LKP / 16; nt += 4) {
    const int brow = nt * 16 + (l & 15);
#pragma unroll
    for (int mt = 0; mt < LQP / 16; ++mt) {
      const int arow = mt * 16 + (l & 15);
      f32x4 a_ = {0.f, 0.f, 0.f, 0.f};
#pragma unroll
      for (int kk = 0; kk < 2; ++kk) {
        bf16x8 av = *(const bf16x8*)&Qs[arow * 64 + (((kk * 4 + (l >> 4)) ^ (arow & 7)) << 3)];
        bf16x8 bv = *(const bf16x8*)&KV[brow * 64 + (((kk * 4 + (l >> 4)) ^ (brow & 7)) << 3)];
        a_ = mfma16(av, bv, a_);
      }
      const int r0 = mt * 16 + (l >> 4) * 4, cc = nt * 16 + (l & 15);
#pragma unroll
      for (int j = 0; j < 4; ++j) Ss[(r0 + j) * LKS + cc] = f2b(a_[j]);
    }
  }
  __syncthreads();

  // stage V transposed into KV (overlaps softmax VALU)
  {
    const int kcol = tid & 31, d8 = tid >> 5;
#pragma unroll
    for (int kb = 0; kb < LKP / 32; ++kb) {
      const int k = kb * 32 + kcol;
      alignas(16) u16 tmp[8] = {0, 0, 0, 0, 0, 0, 0, 0};
      if (k < LK) *(uint4*)tmp = *(const uint4*)(Vg + (size_t)k * 768 + d8 * 8);
#pragma unroll
      for (int j = 0; j < 8; ++j) KV[(d8 * 8 + j) * LKS + k] = tmp[j];
    }
  }
  // softmax in-place on Ss rows
  constexpr int NCH = (LKP + 63) / 64;
  for (int r = w; r < LQ; r += 4) {
    float sv[NCH];
    float mx = -INFINITY;
#pragma unroll
    for (int i = 0; i < NCH; ++i) {
      int c = l + (i << 6);
      float s = -INFINITY;
      if (c < LK) {
        s = b2f(Ss[r * LKS + c]);
        if (MASK && tokLds[c] == 0) s = -1e9f;
      }
      sv[i] = s;
      mx = fmaxf(mx, s);
    }
    for (int d = 1; d < 64; d <<= 1) mx = fmaxf(mx, __shfl_xor(mx, d));
    float sum = 0.f;
#pragma unroll
    for (int i = 0; i < NCH; ++i) { float e = __expf(sv[i] - mx); sv[i] = e; sum += e; }
    for (int d = 1; d < 64; d <<= 1) sum += __shfl_xor(sum, d);
    const float inv = 1.0f / sum;
#pragma unroll
    for (int i = 0; i < NCH; ++i) {
      int c = l + (i << 6);
      if (c < LKP) Ss[r * LKS + c] = f2b(sv[i] * inv);
    }
  }
  __syncthreads();

  // P*V -> O
  for (int mt = w; mt < LQP / 16; mt += 4) {
    const int arow = mt * 16 + (l & 15);
#pragma unroll
    for (int nt = 0; nt < 4; ++nt) {
      f32x4 a_ = {0.f, 0.f, 0.f, 0.f};
#pragma unroll
      for (int kk = 0; kk < LKP; kk += 32) {
        bf16x8 av = *(const bf16x8*)&Ss[arow * LKS + kk + (l >> 4) * 8];
        bf16x8 bv = *(const bf16x8*)&KV[(nt * 16 + (l & 15)) * LKS + kk + (l >> 4) * 8];
        a_ = mfma16(av, bv, a_);
      }
      const int r0 = mt * 16 + (l >> 4) * 4, c16 = l & 15;
#pragma unroll
      for (int j = 0; j < 4; ++j) {
        int r = r0 + j;
        if (r < LQ) O[(qrow0 + r) * 768 + h * 64 + nt * 16 + c16] = f2b(a_[j]);
      }
    }
  }
}

// ---------------------------------------------------------------
extern "C" void kernel_launch(void* const* d_in, const int* in_sizes, int n_in,
                              void* d_out, int out_size, void* d_ws, size_t ws_size,
                              hipStream_t stream) {
  (void)in_sizes; (void)n_in; (void)out_size; (void)ws_size;
  const float* image_feats = (const float*)d_in[0];
  const float* image_att = (const float*)d_in[1];
  const float* text_feats = (const float*)d_in[2];
  const float* text_att = (const float*)d_in[3];
  const int* tokens = (const int*)d_in[4];
  const float* bn_img_g = (const float*)d_in[5];
  const float* bn_img_b = (const float*)d_in[6];
  const float* bn_img_m = (const float*)d_in[7];
  const float* bn_img_v = (const float*)d_in[8];
  const float* bn_txt_g = (const float*)d_in[9];
  const float* bn_txt_b = (const float*)d_in[10];
  const float* bn_txt_m = (const float*)d_in[11];
  const float* bn_txt_v = (const float*)d_in[12];
  const float* ln1_g = (const float*)d_in[13];
  const float* ln1_b = (const float*)d_in[14];
  const float* ln2_g = (const float*)d_in[15];
  const float* ln2_b = (const float*)d_in[16];
  const float* Wq = (const float*)d_in[17];
  const float* Wk = (const float*)d_in[18];
  const float* Wv = (const float*)d_in[19];
  const float* Wo = (const float*)d_in[20];
  const float* bq = (const float*)d_in[21];
  const float* bk = (const float*)d_in[22];
  const float* bv = (const float*)d_in[23];
  const float* bo = (const float*)d_in[24];
  const float* W1 = (const float*)d_in[25];
  const float* b1 = (const float*)d_in[26];
  const float* W2 = (const float*)d_in[27];
  const float* b2 = (const float*)d_in[28];

  float* out = (float*)d_out;
  char* wsp = (char*)d_ws;
  size_t off = 0;
  auto alloc = [&](size_t bytes) -> void* {
    void* p = wsp + off;
    off += (bytes + 255) & ~(size_t)255;
    return p;
  };
  // weights
  u16* WqT = (u16*)alloc(768 * 768 * 2);
  u16* WkT = (u16*)alloc(768 * 768 * 2);
  u16* WvT = (u16*)alloc(768 * 768 * 2);
  u16* WoT = (u16*)alloc(768 * 768 * 2);
  u16* W1T = (u16*)alloc((size_t)768 * 3072 * 2);
  u16* W2T = (u16*)alloc((size_t)768 * 3072 * 2);
  // K/V pipelines (dead after attn; gb aliases this region)
  char* kvbase = (char*)(wsp + off);
  u16* kn_i = (u16*)alloc((size_t)25216 * 768 * 2);
  u16* Kb_i = (u16*)alloc((size_t)25216 * 768 * 2);
  u16* Vb_i = (u16*)alloc((size_t)25216 * 768 * 2);
  u16* kn_t = (u16*)alloc((size_t)8192 * 768 * 2);
  u16* Kb_t = (u16*)alloc((size_t)8192 * 768 * 2);
  u16* Vb_t = (u16*)alloc((size_t)8192 * 768 * 2);
  u16* gb = (u16*)kvbase;  // FF intermediate [20480 x 3072] bf16
  // combined row space: rows 0..15359 image (p,b,60), 15360..20479 text (p,b,20)
  int* sel_i = (int*)alloc(2 * 128 * 60 * 4);
  int* sel_t = (int*)alloc(2 * 128 * 20 * 4);
  u16* qn = (u16*)alloc((size_t)20480 * 768 * 2);
  float* xs = (float*)alloc((size_t)20480 * 768 * 4);
  u16* Qb = (u16*)alloc((size_t)20480 * 768 * 2);

  const dim3 tb(32, 8);
  transpose_k<<<dim3(24, 24), tb, 0, stream>>>(Wq, WqT, 768, 768);
  transpose_k<<<dim3(24, 24), tb, 0, stream>>>(Wk, WkT, 768, 768);
  transpose_k<<<dim3(24, 24), tb, 0, stream>>>(Wv, WvT, 768, 768);
  transpose_k<<<dim3(24, 24), tb, 0, stream>>>(Wo, WoT, 768, 768);
  transpose_k<<<dim3(96, 24), tb, 0, stream>>>(W1, W1T, 768, 3072);
  transpose_k<<<dim3(24, 96), tb, 0, stream>>>(W2, W2T, 3072, 768);

  bn_kernel<<<128, 256, 0, stream>>>(image_feats, 197, bn_img_g, bn_img_b, bn_img_m, bn_img_v, out);
  bn_kernel<<<128, 256, 0, stream>>>(text_feats, 64, bn_txt_g, bn_txt_b, bn_txt_m, bn_txt_v, out + 98304);

  topk_sel<<<128, 256, 0, stream>>>(image_att, 197, 59, sel_i, 60);
  topk_sel<<<128, 256, 0, stream>>>(text_att, 64, 19, sel_t, 20);

  // shared K/V per modality
  ln_rows<<<25216 / 4, 256, 0, stream>>>(image_feats, ln1_g, ln1_b, kn_i);
  gemm_bt<EPI_PLAIN><<<dim3(6, 197), 256, 0, stream>>>(kn_i, WkT, bk, nullptr, Kb_i, 25216, 768, 768);
  gemm_bt<EPI_PLAIN><<<dim3(6, 197), 256, 0, stream>>>(kn_i, WvT, bv, nullptr, Vb_i, 25216, 768, 768);
  ln_rows<<<8192 / 4, 256, 0, stream>>>(text_feats, ln1_g, ln1_b, kn_t);
  gemm_bt<EPI_PLAIN><<<dim3(6, 64), 256, 0, stream>>>(kn_t, WkT, bk, nullptr, Kb_t, 8192, 768, 768);
  gemm_bt<EPI_PLAIN><<<dim3(6, 64), 256, 0, stream>>>(kn_t, WvT, bv, nullptr, Vb_t, 8192, 768, 768);

  // gather both parts of both modalities into the combined row space
  gather_kernel<<<dim3(60, 256), 128, 0, stream>>>(sel_i, kn_i, image_feats, qn, xs, 60, 197);
  gather_kernel<<<dim3(20, 256), 128, 0, stream>>>(sel_t, kn_t, text_feats, qn + (size_t)15360 * 768,
                                                   xs + (size_t)15360 * 768, 20, 64);

  // Q projection (combined, pre-scaled by 1/sqrt(64))
  gemm_bt<EPI_QSCALE><<<dim3(6, 160), 256, 0, stream>>>(qn, WqT, bq, nullptr, Qb, 20480, 768, 768);

  // attention (writes att-out into qn)
  attn2<64, 224, 60, 197, false><<<dim3(12, 256), 256, 0, stream>>>(Qb, Kb_i, Vb_i, nullptr, qn);
  attn2<32, 64, 20, 64, true><<<dim3(12, 256), 256, 0, stream>>>(Qb + (size_t)15360 * 768, Kb_t, Vb_t,
                                                                 tokens, qn + (size_t)15360 * 768);

  // x1 = xs + att@Wo + bo   (in-place on xs)
  gemm_bt<EPI_RES_FADD><<<dim3(6, 160), 256, 0, stream>>>(qn, WoT, bo, xs, xs, 20480, 768, 768);
  // h = LN2(x1)
  ln_rows<<<20480 / 4, 256, 0, stream>>>(xs, ln2_g, ln2_b, Qb);
  // gb = gelu(h@W1 + b1)
  gemm_bt<EPI_GELU><<<dim3(24, 160), 256, 0, stream>>>(Qb, W1T, b1, nullptr, gb, 20480, 3072, 768);
  // out = x1 + gb@W2 + b2
  gemm_bt<EPI_RES_OUT><<<dim3(6, 160), 256, 0, stream>>>(gb, W2T, b2, xs, out + 196608, 20480, 768, 3072);
}